// Round 9
// baseline (177.964 us; speedup 1.0000x reference)
//
#include <hip/hip_runtime.h>
#include <hip/hip_bf16.h>

typedef __bf16 bf16x8 __attribute__((ext_vector_type(8)));
typedef __bf16 bf16x4 __attribute__((ext_vector_type(4)));
typedef __bf16 bf16x2 __attribute__((ext_vector_type(2)));
typedef float  f32x4  __attribute__((ext_vector_type(4)));
typedef float  f32x16 __attribute__((ext_vector_type(16)));
typedef unsigned int u32;
typedef u32 u32x2 __attribute__((ext_vector_type(2)));
typedef u32 u32x4 __attribute__((ext_vector_type(4)));

#define S_  2048
#define E_  1024
#define NH_ 64

__device__ __forceinline__ f32x4 mfma16(bf16x8 a, bf16x8 b, f32x4 c) {
    return __builtin_amdgcn_mfma_f32_16x16x32_bf16(a, b, c, 0, 0, 0);
}
__device__ __forceinline__ f32x16 mfma32(bf16x8 a, bf16x8 b, f32x16 c) {
    return __builtin_amdgcn_mfma_f32_32x32x16_bf16(a, b, c, 0, 0, 0);
}
__device__ __forceinline__ u32 pack2(float a, float b) {
    bf16x2 t; t[0] = (__bf16)a; t[1] = (__bf16)b;
    return __builtin_bit_cast(u32, t);
}
__device__ __forceinline__ void swap32(u32& a, u32& b) {
    asm("v_permlane32_swap_b32 %0, %1" : "+v"(a), "+v"(b));
}
__device__ __forceinline__ f32x16 zero16() {
    f32x16 z;
#pragma unroll
    for (int i = 0; i < 16; ++i) z[i] = 0.f;
    return z;
}
__device__ __forceinline__ void gload_lds16(const void* g, void* l) {
    __builtin_amdgcn_global_load_lds(
        (const __attribute__((address_space(1))) unsigned int*)g,
        (__attribute__((address_space(3))) unsigned int*)l, 16, 0, 0);
}
// fragment = two ds_read_b64; assembled via bit_cast (no per-element VALU)
__device__ __forceinline__ bf16x8 lds_frag(const char* p0, const char* p1) {
    u32x2 lo = *(const u32x2*)p0;
    u32x2 hi = *(const u32x2*)p1;
    u32x4 t; t[0] = lo[0]; t[1] = lo[1]; t[2] = hi[0]; t[3] = hi[1];
    return __builtin_bit_cast(bf16x8, t);
}

// ------------------------------------------- Wo -> bf16 (pre-swizzled cols)
__global__ __launch_bounds__(256) void k_cast_wo(const float* __restrict__ Wo,
                                                 __bf16* __restrict__ Wob) {
    int i = (blockIdx.x * 256 + threadIdx.x) * 8;
    int o = i >> 10, e0 = i & 1023;
    float4 a = *(const float4*)(Wo + i);
    float4 b = *(const float4*)(Wo + i + 4);
    bf16x8 f;
    f[0] = (__bf16)a.x; f[1] = (__bf16)a.y; f[2] = (__bf16)a.z; f[3] = (__bf16)a.w;
    f[4] = (__bf16)b.x; f[5] = (__bf16)b.y; f[6] = (__bf16)b.z; f[7] = (__bf16)b.w;
    int e_swz = (e0 & ~63) | ((e0 & 63) ^ ((o & 7) << 3));
    *(bf16x8*)(Wob + (size_t)o * 1024 + e_swz) = f;
}

// ------------------------------------------------- QKV per-head projections
// Same layouts as before (byte-identical), but outputs routed through an LDS
// tile and copied out row-linear -> fully coalesced 16B global stores.
// z=0 V: Vt[nh][d][s ^ fV(d)], fV=((d&7)<<3)|(((d>>3)&1)<<2)
// z=1 K: Kws[nh][s][e ^ fK(s)], fK=((s&7)<<3)|(((s>>3)&1)<<2)
// z=2 Q: Qws[nh][s][e] plain; log2(e)/32 folded into Wq.
#define TP 72   // padded LDS row stride (elems): breaks copyout bank alignment
__global__ __launch_bounds__(256) void k_proj(const float* __restrict__ vin,
                                              const float* __restrict__ kin,
                                              const float* __restrict__ qin,
                                              const float* __restrict__ Wv,
                                              const float* __restrict__ Wk,
                                              const float* __restrict__ Wq,
                                              __bf16* __restrict__ Qws,
                                              __bf16* __restrict__ Kws,
                                              __bf16* __restrict__ Vt) {
    __shared__ __align__(16) __bf16 tile[64 * TP];   // 9 KB
    const int z = blockIdx.z;
    const float* in = (z == 0) ? vin : ((z == 1) ? kin : qin);
    const float* W  = (z == 0) ? Wv  : ((z == 1) ? Wk  : Wq);
    const float scale = (z == 2) ? 0.04508422f : 1.0f;  // log2(e)/32
    const int bid  = blockIdx.x;
    const int nh   = bid >> 5;
    const int sblk = (bid & 31) << 6;
    const int n = nh >> 4, h = nh & 15;
    const int lane = threadIdx.x & 63, wid = threadIdx.x >> 6;
    const int l16 = lane & 15, g = lane >> 4;

    bf16x8 Bf[4][2];
#pragma unroll
    for (int nt = 0; nt < 4; ++nt)
#pragma unroll
        for (int ks = 0; ks < 2; ++ks) {
            const float* wp = W + (nt * 16 + l16) * 64 + ks * 32 + g * 8;
            float4 a = *(const float4*)wp;
            float4 b = *(const float4*)(wp + 4);
            bf16x8 f;
            f[0] = (__bf16)(a.x * scale); f[1] = (__bf16)(a.y * scale);
            f[2] = (__bf16)(a.z * scale); f[3] = (__bf16)(a.w * scale);
            f[4] = (__bf16)(b.x * scale); f[5] = (__bf16)(b.y * scale);
            f[6] = (__bf16)(b.z * scale); f[7] = (__bf16)(b.w * scale);
            Bf[nt][ks] = f;
        }

    const int s = sblk + wid * 16 + l16;
    const float* ip = in + ((size_t)n * S_ + s) * E_ + h * 64 + g * 8;
    bf16x8 Af[2];
#pragma unroll
    for (int ks = 0; ks < 2; ++ks) {
        float4 a = *(const float4*)(ip + ks * 32);
        float4 b = *(const float4*)(ip + ks * 32 + 4);
        bf16x8 f;
        f[0] = (__bf16)a.x; f[1] = (__bf16)a.y; f[2] = (__bf16)a.z; f[3] = (__bf16)a.w;
        f[4] = (__bf16)b.x; f[5] = (__bf16)b.y; f[6] = (__bf16)b.z; f[7] = (__bf16)b.w;
        Af[ks] = f;
    }

    f32x4 acc[4];
#pragma unroll
    for (int nt = 0; nt < 4; ++nt) { acc[nt][0] = 0.f; acc[nt][1] = 0.f; acc[nt][2] = 0.f; acc[nt][3] = 0.f; }

    if (z == 0) {
        // non-swapped: lane dim = d, reg dim = s-run of 4
#pragma unroll
        for (int nt = 0; nt < 4; ++nt) {
            acc[nt] = mfma16(Af[0], Bf[nt][0], acc[nt]);
            acc[nt] = mfma16(Af[1], Bf[nt][1], acc[nt]);
        }
#pragma unroll
        for (int nt = 0; nt < 4; ++nt) {
            int d = nt * 16 + l16;
            int scol = (wid * 16 + g * 4) ^ (((d & 7) << 3) | (((d >> 3) & 1) << 2));
            bf16x4 o;
#pragma unroll
            for (int r = 0; r < 4; ++r) o[r] = (__bf16)acc[nt][r];
            *(bf16x4*)(tile + d * TP + scol) = o;   // row = d
        }
    } else {
        // swapped: lane dim = s, reg dim = e-run of 4
#pragma unroll
        for (int nt = 0; nt < 4; ++nt) {
            acc[nt] = mfma16(Bf[nt][0], Af[0], acc[nt]);
            acc[nt] = mfma16(Bf[nt][1], Af[1], acc[nt]);
        }
        const int sl = wid * 16 + l16;
        const int fk = (z == 1) ? (((sl & 7) << 3) | (((sl >> 3) & 1) << 2)) : 0;
#pragma unroll
        for (int nt = 0; nt < 4; ++nt) {
            int e0 = (nt * 16 + g * 4) ^ fk;
            bf16x4 o;
#pragma unroll
            for (int r = 0; r < 4; ++r) o[r] = (__bf16)acc[nt][r];
            *(bf16x4*)(tile + sl * TP + e0) = o;    // row = s-local
        }
    }
    __syncthreads();

    // copy out row-linear: thread t -> row t>>2, 32B chunk (t&3)
    const int trow = threadIdx.x >> 2, tc = (threadIdx.x & 3) * 16;
    bf16x8 v0 = *(const bf16x8*)(tile + trow * TP + tc);
    bf16x8 v1 = *(const bf16x8*)(tile + trow * TP + tc + 8);
    __bf16* dst;
    if (z == 0)      dst = Vt  + ((size_t)nh * 64 + trow) * S_ + sblk + tc;
    else if (z == 1) dst = Kws + ((size_t)nh * S_ + sblk + trow) * 64 + tc;
    else             dst = Qws + ((size_t)nh * S_ + sblk + trow) * 64 + tc;
    *(bf16x8*)dst = v0;
    *(bf16x8*)(dst + 8) = v1;
}

// ----------------------------------------------------------- flash attention
// Block: 4 waves x 32 q = 128 q, one (n,h); grid 1024, launch_bounds(256,4)
// -> 4 blocks/CU = 16 waves/CU (TLP to saturate the VALU softmax pipe).
// K/V tiles (8KB+8KB) double-buffered via global_load_lds; ds_read_b64 pairs
// with 4-bit-row XOR swizzle pre-applied in global (conflict-free).
__global__ __launch_bounds__(256, 4) void k_attn(const __bf16* __restrict__ Qws,
                                                 const __bf16* __restrict__ Kws,
                                                 const __bf16* __restrict__ Vt,
                                                 const int* __restrict__ maskp,
                                                 __bf16* __restrict__ Xws) {
    __shared__ __align__(16) char lds[2][16384];  // [buf][K 8KB | V 8KB]
    const int tid = threadIdx.x, lane = tid & 63, wid = tid >> 6;
    const int l31 = lane & 31, hf = lane >> 5, h8 = hf * 8;
    // XCD swizzle: 1024 blocks = 8 xcd x (8 nh x 16 qb); XCD x -> nh [8x,8x+8)
    const int v = blockIdx.x;
    const int u = v >> 3;
    const int nh = (v & 7) * 8 + (u & 7), qb = u >> 3;
    const int n = nh >> 4, hd = nh & 15;

    int az = 0;
    for (int i = tid; i < S_; i += 256) az |= (maskp[(size_t)n * S_ + i] == 0);
    const int anyzero = __syncthreads_or(az);

    const char* Kc = (const char*)(Kws + (size_t)nh * S_ * 64);
    const char* Vc = (const char*)(Vt  + (size_t)nh * 64 * S_);
    const __bf16* Qb = Qws + (size_t)nh * S_ * 64;

    const int q0 = qb * 128 + wid * 32;
    bf16x8 Qf[4];
#pragma unroll
    for (int dt = 0; dt < 4; ++dt)
        Qf[dt] = *(const bf16x8*)(Qb + (size_t)(q0 + l31) * 64 + dt * 16 + h8);

    f32x16 acc0 = zero16(), acc1 = zero16();
    float lsum = 0.f;

    // stage 16KB with 256 threads: 4 x gload_lds16 per thread
    auto stage = [&](int buf, int kb) {
        char* base = &lds[buf][0];
        const char* ks = Kc + (size_t)kb * 8192 + wid * 2048 + lane * 16;
        char* kd = base + wid * 2048;
        gload_lds16(ks, kd);
        gload_lds16(ks + 1024, kd + 1024);
        const int r0 = wid * 16 + (lane >> 3);
        const char* vs = Vc + (size_t)r0 * (S_ * 2) + (size_t)kb * 128 + (lane & 7) * 16;
        char* vd = base + 8192 + wid * 2048;
        gload_lds16(vs, vd);
        gload_lds16(vs + (size_t)8 * (S_ * 2), vd + 1024);
    };

    // 4-bit row XOR, 8B slots: 16 distinct slots -> 2-way max (free)
    const int fs = ((l31 & 7) << 4) | (((l31 >> 3) & 1) << 3);

    auto softmax = [&](const f32x16& s, float& ls, int kbase, bf16x8& P0, bf16x8& P1) {
        f32x16 sv = s;
        if (anyzero) {
#pragma unroll
            for (int r = 0; r < 16; ++r) {
                int kk = kbase + (r & 3) + 8 * (r >> 2) + 4 * hf;
                if (maskp[(size_t)n * S_ + kk] == 0) sv[r] = -1e30f;
            }
        }
        float p[16];
#pragma unroll
        for (int r = 0; r < 16; ++r) p[r] = __builtin_amdgcn_exp2f(sv[r]);
        ls += ((((p[0] + p[1]) + (p[2] + p[3])) + ((p[4] + p[5]) + (p[6] + p[7])))
            + (((p[8] + p[9]) + (p[10] + p[11])) + ((p[12] + p[13]) + (p[14] + p[15]))));
        u32 w0 = pack2(p[0],  p[1]),  w1 = pack2(p[2],  p[3]);
        u32 w2 = pack2(p[4],  p[5]),  w3 = pack2(p[6],  p[7]);
        u32 w4 = pack2(p[8],  p[9]),  w5 = pack2(p[10], p[11]);
        u32 w6 = pack2(p[12], p[13]), w7 = pack2(p[14], p[15]);
        swap32(w0, w2); swap32(w1, w3); swap32(w4, w6); swap32(w5, w7);
        u32x4 t0; t0[0] = w0; t0[1] = w1; t0[2] = w2; t0[3] = w3;
        u32x4 t1; t1[0] = w4; t1[1] = w5; t1[2] = w6; t1[3] = w7;
        P0 = __builtin_bit_cast(bf16x8, t0);
        P1 = __builtin_bit_cast(bf16x8, t1);
    };

    stage(0, 0);
    int buf = 0;
    for (int kb = 0; kb < 32; ++kb) {
        __syncthreads();
        if (kb < 31) stage(buf ^ 1, kb + 1);
        char* base = &lds[buf][0];
        char* vbase = base + 8192;
        const int k0 = kb * 64;
#pragma unroll
        for (int kt = 0; kt < 2; ++kt) {
            const char* krow = base + (kt * 32 + l31) * 128;
            bf16x8 K0 = lds_frag(krow + ((0 * 32 + hf * 16) ^ fs), krow + ((0 * 32 + hf * 16 + 8) ^ fs));
            bf16x8 K1 = lds_frag(krow + ((1 * 32 + hf * 16) ^ fs), krow + ((1 * 32 + hf * 16 + 8) ^ fs));
            bf16x8 K2 = lds_frag(krow + ((2 * 32 + hf * 16) ^ fs), krow + ((2 * 32 + hf * 16 + 8) ^ fs));
            bf16x8 K3 = lds_frag(krow + ((3 * 32 + hf * 16) ^ fs), krow + ((3 * 32 + hf * 16 + 8) ^ fs));
            __builtin_amdgcn_s_setprio(1);
            f32x16 sA = zero16();
            sA = mfma32(K0, Qf[0], sA); sA = mfma32(K1, Qf[1], sA);
            sA = mfma32(K2, Qf[2], sA); sA = mfma32(K3, Qf[3], sA);
            __builtin_amdgcn_s_setprio(0);
            // issue V reads before softmax so ds latency hides under VALU
            const char* v0row = vbase + (0 * 32 + l31) * 128;
            const char* v1row = vbase + (1 * 32 + l31) * 128;
            const int o0b = (kt * 2 + 0) * 32 + hf * 16;
            const int o1b = (kt * 2 + 1) * 32 + hf * 16;
            bf16x8 V00 = lds_frag(v0row + (o0b ^ fs), v0row + ((o0b + 8) ^ fs));
            bf16x8 V01 = lds_frag(v0row + (o1b ^ fs), v0row + ((o1b + 8) ^ fs));
            bf16x8 V10 = lds_frag(v1row + (o0b ^ fs), v1row + ((o0b + 8) ^ fs));
            bf16x8 V11 = lds_frag(v1row + (o1b ^ fs), v1row + ((o1b + 8) ^ fs));
            bf16x8 P0, P1;
            softmax(sA, lsum, k0 + kt * 32, P0, P1);
            __builtin_amdgcn_s_setprio(1);
            acc0 = mfma32(V00, P0, acc0); acc0 = mfma32(V01, P1, acc0);
            acc1 = mfma32(V10, P0, acc1); acc1 = mfma32(V11, P1, acc1);
            __builtin_amdgcn_s_setprio(0);
        }
        buf ^= 1;
    }

    lsum += __shfl_xor(lsum, 32);
    const float inv = 1.0f / lsum;
    const int qg = q0 + l31;
    __bf16* Ob = Xws + ((size_t)(n * S_ + qg)) * E_ + hd * 64;
    const int qsw = (qg & 7) << 3;

    auto store_half = [&](const f32x16& a, int dv) {
#pragma unroll
        for (int rr = 0; rr < 4; ++rr) {
            bf16x4 o;
#pragma unroll
            for (int j = 0; j < 4; ++j) o[j] = (__bf16)(a[rr * 4 + j] * inv);
            int dsw = ((dv * 32 + rr * 8) ^ qsw) + hf * 4;  // pre-swizzle for k_out
            *(bf16x4*)(Ob + dsw) = o;
        }
    };
    store_half(acc0, 0);
    store_half(acc1, 1);
}

// ------------------------------------------------------- output GEMM + bias
// 128x128 block tile, BK=64, LDS-staged (global_load_lds, double-buffered),
// swizzled ds_read_b128 (swizzle pre-applied in global X / Wob).
__global__ __launch_bounds__(256) void k_out(const __bf16* __restrict__ Xws,
                                             const __bf16* __restrict__ Wob,
                                             const float* __restrict__ bo,
                                             float* __restrict__ out) {
    __shared__ __align__(16) char Al[2][16384];
    __shared__ __align__(16) char Bl[2][16384];
    const int tid = threadIdx.x, lane = tid & 63, wid = tid >> 6;
    const int l31 = lane & 31, hf = lane >> 5;
    const int v = blockIdx.x;
    const int id2 = (v & 7) * 64 + (v >> 3);
    const int mb = id2 >> 3, ob = id2 & 7;
    const int m0 = mb * 128, o0 = ob * 128;
    const int wr = wid >> 1, wc = wid & 1;

    const char* Xb = (const char*)Xws + (size_t)m0 * 2048;
    const char* Wb = (const char*)Wob + (size_t)o0 * 2048;
    const int r = tid >> 3, cb = (tid & 7) * 16;

    auto stage = [&](int buf, int kb) {
#pragma unroll
        for (int p = 0; p < 4; ++p) {
            gload_lds16(Xb + (size_t)(p * 32 + r) * 2048 + kb * 128 + cb,
                        &Al[buf][p * 4096 + wid * 1024]);
            gload_lds16(Wb + (size_t)(p * 32 + r) * 2048 + kb * 128 + cb,
                        &Bl[buf][p * 4096 + wid * 1024]);
        }
    };

    f32x16 acc00 = zero16(), acc01 = zero16(), acc10 = zero16(), acc11 = zero16();

    const int arow0 = (wr * 64 + l31) * 128;
    const int brow0 = (wc * 64 + l31) * 128;
    const int rsw = (l31 & 7) << 4;

    stage(0, 0);
    int buf = 0;
    for (int kb = 0; kb < 16; ++kb) {
        __syncthreads();
        if (kb < 15) stage(buf ^ 1, kb + 1);
        const char* ab = &Al[buf][0];
        const char* bb = &Bl[buf][0];
#pragma unroll
        for (int ks = 0; ks < 4; ++ks) {
            const int co = (ks * 32 + hf * 16) ^ rsw;
            bf16x8 A0 = *(const bf16x8*)(ab + arow0 + co);
            bf16x8 A1 = *(const bf16x8*)(ab + arow0 + 32 * 128 + co);
            bf16x8 B0 = *(const bf16x8*)(bb + brow0 + co);
            bf16x8 B1 = *(const bf16x8*)(bb + brow0 + 32 * 128 + co);
            __builtin_amdgcn_s_setprio(1);
            acc00 = mfma32(A0, B0, acc00);
            acc01 = mfma32(A0, B1, acc01);
            acc10 = mfma32(A1, B0, acc10);
            acc11 = mfma32(A1, B1, acc11);
            __builtin_amdgcn_s_setprio(0);
        }
        buf ^= 1;
    }

    const float bias0 = bo[o0 + wc * 64 + l31];
    const float bias1 = bo[o0 + wc * 64 + 32 + l31];
#pragma unroll
    for (int sm = 0; sm < 2; ++sm) {
        const f32x16& a0 = (sm == 0) ? acc00 : acc10;
        const f32x16& a1 = (sm == 0) ? acc01 : acc11;
#pragma unroll
        for (int rr = 0; rr < 4; ++rr)
#pragma unroll
            for (int j = 0; j < 4; ++j) {
                size_t m = (size_t)m0 + wr * 64 + sm * 32 + rr * 8 + hf * 4 + j;
                out[m * E_ + o0 + wc * 64 + l31]      = a0[rr * 4 + j] + bias0;
                out[m * E_ + o0 + wc * 64 + 32 + l31] = a1[rr * 4 + j] + bias1;
            }
    }
}

extern "C" void kernel_launch(void* const* d_in, const int* in_sizes, int n_in,
                              void* d_out, int out_size, void* d_ws, size_t ws_size,
                              hipStream_t stream) {
    const float* vin  = (const float*)d_in[0];
    const float* kin  = (const float*)d_in[1];
    const float* qin  = (const float*)d_in[2];
    const int*   mask = (const int*)d_in[3];
    const float* Wv   = (const float*)d_in[4];
    const float* Wk   = (const float*)d_in[5];
    const float* Wq   = (const float*)d_in[6];
    const float* Wo   = (const float*)d_in[7];
    const float* bo   = (const float*)d_in[8];

    __bf16* Qws = (__bf16*)d_ws;                       // [64][2048][64]
    __bf16* Kws = Qws + (size_t)NH_ * S_ * 64;         // [64][2048][64] swizzled
    __bf16* Vt  = Kws + (size_t)NH_ * S_ * 64;         // [64][64][2048] swizzled
    __bf16* Xws = Vt  + (size_t)NH_ * S_ * 64;         // [4][2048][1024] swizzled
    __bf16* Wob = Xws + (size_t)4 * S_ * E_;           // [1024][1024] swizzled
    float* out = (float*)d_out;

    hipLaunchKernelGGL(k_cast_wo, dim3(512), dim3(256), 0, stream, Wo, Wob);
    hipLaunchKernelGGL(k_proj, dim3(2048, 1, 3), dim3(256), 0, stream,
                       vin, kin, qin, Wv, Wk, Wq, Qws, Kws, Vt);
    hipLaunchKernelGGL(k_attn, dim3(1024), dim3(256), 0, stream, Qws, Kws, Vt, mask, Xws);
    hipLaunchKernelGGL(k_out, dim3(512), dim3(256), 0, stream, Xws, Wob, bo, out);
}

// Round 10
// 173.934 us; speedup vs baseline: 1.0232x; 1.0232x over previous
//
#include <hip/hip_runtime.h>
#include <hip/hip_bf16.h>

typedef __bf16 bf16x8 __attribute__((ext_vector_type(8)));
typedef __bf16 bf16x4 __attribute__((ext_vector_type(4)));
typedef __bf16 bf16x2 __attribute__((ext_vector_type(2)));
typedef float  f32x4  __attribute__((ext_vector_type(4)));
typedef float  f32x16 __attribute__((ext_vector_type(16)));
typedef unsigned int u32;
typedef u32 u32x2 __attribute__((ext_vector_type(2)));
typedef u32 u32x4 __attribute__((ext_vector_type(4)));

#define S_  2048
#define E_  1024
#define NH_ 64

__device__ __forceinline__ f32x4 mfma16(bf16x8 a, bf16x8 b, f32x4 c) {
    return __builtin_amdgcn_mfma_f32_16x16x32_bf16(a, b, c, 0, 0, 0);
}
__device__ __forceinline__ f32x16 mfma32(bf16x8 a, bf16x8 b, f32x16 c) {
    return __builtin_amdgcn_mfma_f32_32x32x16_bf16(a, b, c, 0, 0, 0);
}
__device__ __forceinline__ u32 pack2(float a, float b) {
    bf16x2 t; t[0] = (__bf16)a; t[1] = (__bf16)b;
    return __builtin_bit_cast(u32, t);
}
__device__ __forceinline__ void swap32(u32& a, u32& b) {
    asm("v_permlane32_swap_b32 %0, %1" : "+v"(a), "+v"(b));
}
__device__ __forceinline__ f32x16 zero16() {
    f32x16 z;
#pragma unroll
    for (int i = 0; i < 16; ++i) z[i] = 0.f;
    return z;
}
__device__ __forceinline__ void gload_lds16(const void* g, void* l) {
    __builtin_amdgcn_global_load_lds(
        (const __attribute__((address_space(1))) unsigned int*)g,
        (__attribute__((address_space(3))) unsigned int*)l, 16, 0, 0);
}

// ------------------------------------------- Wo -> bf16 (pre-swizzled cols)
__global__ __launch_bounds__(256) void k_cast_wo(const float* __restrict__ Wo,
                                                 __bf16* __restrict__ Wob) {
    int i = (blockIdx.x * 256 + threadIdx.x) * 8;
    int o = i >> 10, e0 = i & 1023;
    float4 a = *(const float4*)(Wo + i);
    float4 b = *(const float4*)(Wo + i + 4);
    bf16x8 f;
    f[0] = (__bf16)a.x; f[1] = (__bf16)a.y; f[2] = (__bf16)a.z; f[3] = (__bf16)a.w;
    f[4] = (__bf16)b.x; f[5] = (__bf16)b.y; f[6] = (__bf16)b.z; f[7] = (__bf16)b.w;
    int e_swz = (e0 & ~63) | ((e0 & 63) ^ ((o & 7) << 3));
    *(bf16x8*)(Wob + (size_t)o * 1024 + e_swz) = f;
}

// ------------------------------------------------- QKV per-head projections
// Outputs routed through an LDS tile, copied out row-linear (coalesced 16B).
// z=0 V: Vt[nh][d][s ^ ((d&7)<<3)]   (16B-granularity swizzle for b128 reads)
// z=1 K: Kws[nh][s][e ^ ((s&7)<<3)]
// z=2 Q: Qws[nh][s][e] plain; log2(e)/32 folded into Wq.
#define TP 72   // padded LDS row stride (elems)
__global__ __launch_bounds__(256) void k_proj(const float* __restrict__ vin,
                                              const float* __restrict__ kin,
                                              const float* __restrict__ qin,
                                              const float* __restrict__ Wv,
                                              const float* __restrict__ Wk,
                                              const float* __restrict__ Wq,
                                              __bf16* __restrict__ Qws,
                                              __bf16* __restrict__ Kws,
                                              __bf16* __restrict__ Vt) {
    __shared__ __align__(16) __bf16 tile[64 * TP];   // 9 KB
    const int z = blockIdx.z;
    const float* in = (z == 0) ? vin : ((z == 1) ? kin : qin);
    const float* W  = (z == 0) ? Wv  : ((z == 1) ? Wk  : Wq);
    const float scale = (z == 2) ? 0.04508422f : 1.0f;  // log2(e)/32
    const int bid  = blockIdx.x;
    const int nh   = bid >> 5;
    const int sblk = (bid & 31) << 6;
    const int n = nh >> 4, h = nh & 15;
    const int lane = threadIdx.x & 63, wid = threadIdx.x >> 6;
    const int l16 = lane & 15, g = lane >> 4;

    bf16x8 Bf[4][2];
#pragma unroll
    for (int nt = 0; nt < 4; ++nt)
#pragma unroll
        for (int ks = 0; ks < 2; ++ks) {
            const float* wp = W + (nt * 16 + l16) * 64 + ks * 32 + g * 8;
            float4 a = *(const float4*)wp;
            float4 b = *(const float4*)(wp + 4);
            bf16x8 f;
            f[0] = (__bf16)(a.x * scale); f[1] = (__bf16)(a.y * scale);
            f[2] = (__bf16)(a.z * scale); f[3] = (__bf16)(a.w * scale);
            f[4] = (__bf16)(b.x * scale); f[5] = (__bf16)(b.y * scale);
            f[6] = (__bf16)(b.z * scale); f[7] = (__bf16)(b.w * scale);
            Bf[nt][ks] = f;
        }

    const int s = sblk + wid * 16 + l16;
    const float* ip = in + ((size_t)n * S_ + s) * E_ + h * 64 + g * 8;
    bf16x8 Af[2];
#pragma unroll
    for (int ks = 0; ks < 2; ++ks) {
        float4 a = *(const float4*)(ip + ks * 32);
        float4 b = *(const float4*)(ip + ks * 32 + 4);
        bf16x8 f;
        f[0] = (__bf16)a.x; f[1] = (__bf16)a.y; f[2] = (__bf16)a.z; f[3] = (__bf16)a.w;
        f[4] = (__bf16)b.x; f[5] = (__bf16)b.y; f[6] = (__bf16)b.z; f[7] = (__bf16)b.w;
        Af[ks] = f;
    }

    f32x4 acc[4];
#pragma unroll
    for (int nt = 0; nt < 4; ++nt) { acc[nt][0] = 0.f; acc[nt][1] = 0.f; acc[nt][2] = 0.f; acc[nt][3] = 0.f; }

    if (z == 0) {
        // non-swapped: lane dim = d, reg dim = s-run of 4
#pragma unroll
        for (int nt = 0; nt < 4; ++nt) {
            acc[nt] = mfma16(Af[0], Bf[nt][0], acc[nt]);
            acc[nt] = mfma16(Af[1], Bf[nt][1], acc[nt]);
        }
#pragma unroll
        for (int nt = 0; nt < 4; ++nt) {
            int d = nt * 16 + l16;
            int scol = (wid * 16 + g * 4) ^ ((d & 7) << 3);
            bf16x4 o;
#pragma unroll
            for (int r = 0; r < 4; ++r) o[r] = (__bf16)acc[nt][r];
            *(bf16x4*)(tile + d * TP + scol) = o;   // row = d
        }
    } else {
        // swapped: lane dim = s, reg dim = e-run of 4
#pragma unroll
        for (int nt = 0; nt < 4; ++nt) {
            acc[nt] = mfma16(Bf[nt][0], Af[0], acc[nt]);
            acc[nt] = mfma16(Bf[nt][1], Af[1], acc[nt]);
        }
        const int sl = wid * 16 + l16;
        const int fk = (z == 1) ? ((sl & 7) << 3) : 0;
#pragma unroll
        for (int nt = 0; nt < 4; ++nt) {
            int e0 = (nt * 16 + g * 4) ^ fk;
            bf16x4 o;
#pragma unroll
            for (int r = 0; r < 4; ++r) o[r] = (__bf16)acc[nt][r];
            *(bf16x4*)(tile + sl * TP + e0) = o;    // row = s-local
        }
    }
    __syncthreads();

    // copy out row-linear: thread t -> row t>>2, 32B chunk (t&3)
    const int trow = threadIdx.x >> 2, tc = (threadIdx.x & 3) * 16;
    bf16x8 v0 = *(const bf16x8*)(tile + trow * TP + tc);
    bf16x8 v1 = *(const bf16x8*)(tile + trow * TP + tc + 8);
    __bf16* dst;
    if (z == 0)      dst = Vt  + ((size_t)nh * 64 + trow) * S_ + sblk + tc;
    else if (z == 1) dst = Kws + ((size_t)nh * S_ + sblk + trow) * 64 + tc;
    else             dst = Qws + ((size_t)nh * S_ + sblk + trow) * 64 + tc;
    *(bf16x8*)dst = v0;
    *(bf16x8*)(dst + 8) = v1;
}

// ----------------------------------------------------------- flash attention
// r5 structure (b128 reads, 16B swizzle, 4 waves x 32 q, lb(256,4), grid 1024)
// + VALU cuts: lsum via ones-MFMA (no add-tree, no final shfl), XOR-folded
// LDS addresses (1 v_xor per fragment read).
__global__ __launch_bounds__(256, 4) void k_attn(const __bf16* __restrict__ Qws,
                                                 const __bf16* __restrict__ Kws,
                                                 const __bf16* __restrict__ Vt,
                                                 const int* __restrict__ maskp,
                                                 __bf16* __restrict__ Xws) {
    __shared__ __align__(16) char lds[2][16384];  // [buf][K 8KB | V 8KB]
    const int tid = threadIdx.x, lane = tid & 63, wid = tid >> 6;
    const int l31 = lane & 31, hf = lane >> 5, h8 = hf * 8;
    // XCD swizzle: 1024 blocks = 8 xcd x (8 nh x 16 qb); XCD x -> nh [8x,8x+8)
    const int v = blockIdx.x;
    const int u = v >> 3;
    const int nh = (v & 7) * 8 + (u & 7), qb = u >> 3;
    const int n = nh >> 4, hd = nh & 15;

    int az = 0;
    for (int i = tid; i < S_; i += 256) az |= (maskp[(size_t)n * S_ + i] == 0);
    const int anyzero = __syncthreads_or(az);

    const char* Kc = (const char*)(Kws + (size_t)nh * S_ * 64);
    const char* Vc = (const char*)(Vt  + (size_t)nh * 64 * S_);
    const __bf16* Qb = Qws + (size_t)nh * S_ * 64;

    const int q0 = qb * 128 + wid * 32;
    bf16x8 Qf[4];
#pragma unroll
    for (int dt = 0; dt < 4; ++dt)
        Qf[dt] = *(const bf16x8*)(Qb + (size_t)(q0 + l31) * 64 + dt * 16 + h8);

    f32x16 acc0 = zero16(), acc1 = zero16(), accl = zero16();
    u32x4 onet; onet[0] = 0x3F803F80u; onet[1] = 0x3F803F80u;
    onet[2] = 0x3F803F80u; onet[3] = 0x3F803F80u;
    const bf16x8 ones = __builtin_bit_cast(bf16x8, onet);

    // stage 16KB with 256 threads: 4 x gload_lds16 per thread
    auto stage = [&](int buf, int kb) {
        char* base = &lds[buf][0];
        const char* ks = Kc + (size_t)kb * 8192 + wid * 2048 + lane * 16;
        char* kd = base + wid * 2048;
        gload_lds16(ks, kd);
        gload_lds16(ks + 1024, kd + 1024);
        const int r0 = wid * 16 + (lane >> 3);
        const char* vs = Vc + (size_t)r0 * (S_ * 2) + (size_t)kb * 128 + (lane & 7) * 16;
        char* vd = base + 8192 + wid * 2048;
        gload_lds16(vs, vd);
        gload_lds16(vs + (size_t)8 * (S_ * 2), vd + 1024);
    };

    // fold swizzle + hf-slot into the base: every read = base ^ compile-const
    const int fold = (hf * 16) ^ ((l31 & 7) << 4);
    const int kb2 = l31 * 128 + fold;          // K row base (bits 4-6 = fold)
    const int vb2 = 8192 + l31 * 128 + fold;   // V row base

    stage(0, 0);
    int buf = 0;
    for (int kb = 0; kb < 32; ++kb) {
        __syncthreads();
        if (kb < 31) stage(buf ^ 1, kb + 1);
        char* base = &lds[buf][0];
        const int k0 = kb * 64;
#pragma unroll
        for (int kt = 0; kt < 2; ++kt) {
            bf16x8 K0 = *(const bf16x8*)(base + ((kb2 ^  0) + kt * 4096));
            bf16x8 K1 = *(const bf16x8*)(base + ((kb2 ^ 32) + kt * 4096));
            bf16x8 K2 = *(const bf16x8*)(base + ((kb2 ^ 64) + kt * 4096));
            bf16x8 K3 = *(const bf16x8*)(base + ((kb2 ^ 96) + kt * 4096));
            __builtin_amdgcn_s_setprio(1);
            f32x16 s = zero16();
            s = mfma32(K0, Qf[0], s); s = mfma32(K1, Qf[1], s);
            s = mfma32(K2, Qf[2], s); s = mfma32(K3, Qf[3], s);
            __builtin_amdgcn_s_setprio(0);
            // issue V reads before softmax so ds latency hides under VALU
            bf16x8 V00 = *(const bf16x8*)(base + (vb2 ^ (kt * 64)));
            bf16x8 V01 = *(const bf16x8*)(base + (vb2 ^ (kt * 64 + 32)));
            bf16x8 V10 = *(const bf16x8*)(base + ((vb2 ^ (kt * 64)) + 4096));
            bf16x8 V11 = *(const bf16x8*)(base + ((vb2 ^ (kt * 64 + 32)) + 4096));
            if (anyzero) {
#pragma unroll
                for (int r = 0; r < 16; ++r) {
                    int kk = k0 + kt * 32 + (r & 3) + 8 * (r >> 2) + 4 * hf;
                    if (maskp[(size_t)n * S_ + kk] == 0) s[r] = -1e30f;
                }
            }
            f32x16 pv;
#pragma unroll
            for (int r = 0; r < 16; ++r) pv[r] = __builtin_amdgcn_exp2f(s[r]);
            u32 w0 = pack2(pv[0],  pv[1]),  w1 = pack2(pv[2],  pv[3]);
            u32 w2 = pack2(pv[4],  pv[5]),  w3 = pack2(pv[6],  pv[7]);
            u32 w4 = pack2(pv[8],  pv[9]),  w5 = pack2(pv[10], pv[11]);
            u32 w6 = pack2(pv[12], pv[13]), w7 = pack2(pv[14], pv[15]);
            swap32(w0, w2); swap32(w1, w3); swap32(w4, w6); swap32(w5, w7);
            u32x4 t0; t0[0] = w0; t0[1] = w1; t0[2] = w2; t0[3] = w3;
            u32x4 t1; t1[0] = w4; t1[1] = w5; t1[2] = w6; t1[3] = w7;
            bf16x8 P0 = __builtin_bit_cast(bf16x8, t0);
            bf16x8 P1 = __builtin_bit_cast(bf16x8, t1);
            __builtin_amdgcn_s_setprio(1);
            acc0 = mfma32(V00, P0, acc0); acc0 = mfma32(V01, P1, acc0);
            acc1 = mfma32(V10, P0, acc1); acc1 = mfma32(V11, P1, acc1);
            accl = mfma32(ones, P0, accl); accl = mfma32(ones, P1, accl);
            __builtin_amdgcn_s_setprio(0);
        }
        buf ^= 1;
    }

    // accl[r][lane] = sum_k P[k][q=lane&31] (identical in every reg, both halves)
    const float inv = 1.0f / accl[0];
    const int qg = q0 + l31;
    __bf16* Ob = Xws + ((size_t)(n * S_ + qg)) * E_ + hd * 64;
    const int qsw = (qg & 7) << 3;

    auto store_half = [&](const f32x16& a, int dv) {
#pragma unroll
        for (int rr = 0; rr < 4; ++rr) {
            bf16x4 o;
#pragma unroll
            for (int j = 0; j < 4; ++j) o[j] = (__bf16)(a[rr * 4 + j] * inv);
            int dsw = ((dv * 32 + rr * 8) ^ qsw) + hf * 4;  // pre-swizzle for k_out
            *(bf16x4*)(Ob + dsw) = o;
        }
    };
    store_half(acc0, 0);
    store_half(acc1, 1);
}

// ------------------------------------------------------- output GEMM + bias
// 128x128 block tile, BK=64, LDS-staged (global_load_lds, double-buffered),
// swizzled ds_read_b128 (swizzle pre-applied in global X / Wob).
__global__ __launch_bounds__(256) void k_out(const __bf16* __restrict__ Xws,
                                             const __bf16* __restrict__ Wob,
                                             const float* __restrict__ bo,
                                             float* __restrict__ out) {
    __shared__ __align__(16) char Al[2][16384];
    __shared__ __align__(16) char Bl[2][16384];
    const int tid = threadIdx.x, lane = tid & 63, wid = tid >> 6;
    const int l31 = lane & 31, hf = lane >> 5;
    const int v = blockIdx.x;
    const int id2 = (v & 7) * 64 + (v >> 3);
    const int mb = id2 >> 3, ob = id2 & 7;
    const int m0 = mb * 128, o0 = ob * 128;
    const int wr = wid >> 1, wc = wid & 1;

    const char* Xb = (const char*)Xws + (size_t)m0 * 2048;
    const char* Wb = (const char*)Wob + (size_t)o0 * 2048;
    const int r = tid >> 3, cb = (tid & 7) * 16;

    auto stage = [&](int buf, int kb) {
#pragma unroll
        for (int p = 0; p < 4; ++p) {
            gload_lds16(Xb + (size_t)(p * 32 + r) * 2048 + kb * 128 + cb,
                        &Al[buf][p * 4096 + wid * 1024]);
            gload_lds16(Wb + (size_t)(p * 32 + r) * 2048 + kb * 128 + cb,
                        &Bl[buf][p * 4096 + wid * 1024]);
        }
    };

    f32x16 acc00 = zero16(), acc01 = zero16(), acc10 = zero16(), acc11 = zero16();

    const int arow0 = (wr * 64 + l31) * 128;
    const int brow0 = (wc * 64 + l31) * 128;
    const int rsw = (l31 & 7) << 4;

    stage(0, 0);
    int buf = 0;
    for (int kb = 0; kb < 16; ++kb) {
        __syncthreads();
        if (kb < 15) stage(buf ^ 1, kb + 1);
        const char* ab = &Al[buf][0];
        const char* bb = &Bl[buf][0];
#pragma unroll
        for (int ks = 0; ks < 4; ++ks) {
            const int co = (ks * 32 + hf * 16) ^ rsw;
            bf16x8 A0 = *(const bf16x8*)(ab + arow0 + co);
            bf16x8 A1 = *(const bf16x8*)(ab + arow0 + 32 * 128 + co);
            bf16x8 B0 = *(const bf16x8*)(bb + brow0 + co);
            bf16x8 B1 = *(const bf16x8*)(bb + brow0 + 32 * 128 + co);
            __builtin_amdgcn_s_setprio(1);
            acc00 = mfma32(A0, B0, acc00);
            acc01 = mfma32(A0, B1, acc01);
            acc10 = mfma32(A1, B0, acc10);
            acc11 = mfma32(A1, B1, acc11);
            __builtin_amdgcn_s_setprio(0);
        }
        buf ^= 1;
    }

    const float bias0 = bo[o0 + wc * 64 + l31];
    const float bias1 = bo[o0 + wc * 64 + 32 + l31];
#pragma unroll
    for (int sm = 0; sm < 2; ++sm) {
        const f32x16& a0 = (sm == 0) ? acc00 : acc10;
        const f32x16& a1 = (sm == 0) ? acc01 : acc11;
#pragma unroll
        for (int rr = 0; rr < 4; ++rr)
#pragma unroll
            for (int j = 0; j < 4; ++j) {
                size_t m = (size_t)m0 + wr * 64 + sm * 32 + rr * 8 + hf * 4 + j;
                out[m * E_ + o0 + wc * 64 + l31]      = a0[rr * 4 + j] + bias0;
                out[m * E_ + o0 + wc * 64 + 32 + l31] = a1[rr * 4 + j] + bias1;
            }
    }
}

extern "C" void kernel_launch(void* const* d_in, const int* in_sizes, int n_in,
                              void* d_out, int out_size, void* d_ws, size_t ws_size,
                              hipStream_t stream) {
    const float* vin  = (const float*)d_in[0];
    const float* kin  = (const float*)d_in[1];
    const float* qin  = (const float*)d_in[2];
    const int*   mask = (const int*)d_in[3];
    const float* Wv   = (const float*)d_in[4];
    const float* Wk   = (const float*)d_in[5];
    const float* Wq   = (const float*)d_in[6];
    const float* Wo   = (const float*)d_in[7];
    const float* bo   = (const float*)d_in[8];

    __bf16* Qws = (__bf16*)d_ws;                       // [64][2048][64]
    __bf16* Kws = Qws + (size_t)NH_ * S_ * 64;         // [64][2048][64] swizzled
    __bf16* Vt  = Kws + (size_t)NH_ * S_ * 64;         // [64][64][2048] swizzled
    __bf16* Xws = Vt  + (size_t)NH_ * S_ * 64;         // [4][2048][1024] swizzled
    __bf16* Wob = Xws + (size_t)4 * S_ * E_;           // [1024][1024] swizzled
    float* out = (float*)d_out;

    hipLaunchKernelGGL(k_cast_wo, dim3(512), dim3(256), 0, stream, Wo, Wob);
    hipLaunchKernelGGL(k_proj, dim3(2048, 1, 3), dim3(256), 0, stream,
                       vin, kin, qin, Wv, Wk, Wq, Qws, Kws, Vt);
    hipLaunchKernelGGL(k_attn, dim3(1024), dim3(256), 0, stream, Qws, Kws, Vt, mask, Xws);
    hipLaunchKernelGGL(k_out, dim3(512), dim3(256), 0, stream, Xws, Wob, bo, out);
}

// Round 11
// 173.442 us; speedup vs baseline: 1.0261x; 1.0028x over previous
//
#include <hip/hip_runtime.h>
#include <hip/hip_bf16.h>

typedef __bf16 bf16x8 __attribute__((ext_vector_type(8)));
typedef __bf16 bf16x4 __attribute__((ext_vector_type(4)));
typedef __bf16 bf16x2 __attribute__((ext_vector_type(2)));
typedef float  f32x4  __attribute__((ext_vector_type(4)));
typedef float  f32x16 __attribute__((ext_vector_type(16)));
typedef unsigned int u32;
typedef u32 u32x2 __attribute__((ext_vector_type(2)));
typedef u32 u32x4 __attribute__((ext_vector_type(4)));

#define S_  2048
#define E_  1024
#define NH_ 64

__device__ __forceinline__ f32x4 mfma16(bf16x8 a, bf16x8 b, f32x4 c) {
    return __builtin_amdgcn_mfma_f32_16x16x32_bf16(a, b, c, 0, 0, 0);
}
__device__ __forceinline__ f32x16 mfma32(bf16x8 a, bf16x8 b, f32x16 c) {
    return __builtin_amdgcn_mfma_f32_32x32x16_bf16(a, b, c, 0, 0, 0);
}
__device__ __forceinline__ u32 pack2(float a, float b) {
    bf16x2 t; t[0] = (__bf16)a; t[1] = (__bf16)b;
    return __builtin_bit_cast(u32, t);
}
__device__ __forceinline__ void swap32(u32& a, u32& b) {
    asm("v_permlane32_swap_b32 %0, %1" : "+v"(a), "+v"(b));
}
__device__ __forceinline__ f32x16 zero16() {
    f32x16 z;
#pragma unroll
    for (int i = 0; i < 16; ++i) z[i] = 0.f;
    return z;
}
__device__ __forceinline__ void gload_lds16(const void* g, void* l) {
    __builtin_amdgcn_global_load_lds(
        (const __attribute__((address_space(1))) unsigned int*)g,
        (__attribute__((address_space(3))) unsigned int*)l, 16, 0, 0);
}

// ------------------------------------------- Wo -> bf16 (pre-swizzled cols)
__global__ __launch_bounds__(256) void k_cast_wo(const float* __restrict__ Wo,
                                                 __bf16* __restrict__ Wob) {
    int i = (blockIdx.x * 256 + threadIdx.x) * 8;
    int o = i >> 10, e0 = i & 1023;
    float4 a = *(const float4*)(Wo + i);
    float4 b = *(const float4*)(Wo + i + 4);
    bf16x8 f;
    f[0] = (__bf16)a.x; f[1] = (__bf16)a.y; f[2] = (__bf16)a.z; f[3] = (__bf16)a.w;
    f[4] = (__bf16)b.x; f[5] = (__bf16)b.y; f[6] = (__bf16)b.z; f[7] = (__bf16)b.w;
    int e_swz = (e0 & ~63) | ((e0 & 63) ^ ((o & 7) << 3));
    *(bf16x8*)(Wob + (size_t)o * 1024 + e_swz) = f;
}

// ------------------------------------------------- QKV per-head projections
// Outputs routed through an LDS tile, copied out row-linear (coalesced 16B).
// z=0 V: Vt[nh][d][s ^ ((d&7)<<3)]   (16B-granularity swizzle for b128 reads)
// z=1 K: Kws[nh][s][e ^ ((s&7)<<3)]
// z=2 Q: Qws[nh][s][e] plain; log2(e)/32 folded into Wq.
#define TP 72   // padded LDS row stride (elems)
__global__ __launch_bounds__(256) void k_proj(const float* __restrict__ vin,
                                              const float* __restrict__ kin,
                                              const float* __restrict__ qin,
                                              const float* __restrict__ Wv,
                                              const float* __restrict__ Wk,
                                              const float* __restrict__ Wq,
                                              __bf16* __restrict__ Qws,
                                              __bf16* __restrict__ Kws,
                                              __bf16* __restrict__ Vt) {
    __shared__ __align__(16) __bf16 tile[64 * TP];   // 9 KB
    const int z = blockIdx.z;
    const float* in = (z == 0) ? vin : ((z == 1) ? kin : qin);
    const float* W  = (z == 0) ? Wv  : ((z == 1) ? Wk  : Wq);
    const float scale = (z == 2) ? 0.04508422f : 1.0f;  // log2(e)/32
    const int bid  = blockIdx.x;
    const int nh   = bid >> 5;
    const int sblk = (bid & 31) << 6;
    const int n = nh >> 4, h = nh & 15;
    const int lane = threadIdx.x & 63, wid = threadIdx.x >> 6;
    const int l16 = lane & 15, g = lane >> 4;

    bf16x8 Bf[4][2];
#pragma unroll
    for (int nt = 0; nt < 4; ++nt)
#pragma unroll
        for (int ks = 0; ks < 2; ++ks) {
            const float* wp = W + (nt * 16 + l16) * 64 + ks * 32 + g * 8;
            float4 a = *(const float4*)wp;
            float4 b = *(const float4*)(wp + 4);
            bf16x8 f;
            f[0] = (__bf16)(a.x * scale); f[1] = (__bf16)(a.y * scale);
            f[2] = (__bf16)(a.z * scale); f[3] = (__bf16)(a.w * scale);
            f[4] = (__bf16)(b.x * scale); f[5] = (__bf16)(b.y * scale);
            f[6] = (__bf16)(b.z * scale); f[7] = (__bf16)(b.w * scale);
            Bf[nt][ks] = f;
        }

    const int s = sblk + wid * 16 + l16;
    const float* ip = in + ((size_t)n * S_ + s) * E_ + h * 64 + g * 8;
    bf16x8 Af[2];
#pragma unroll
    for (int ks = 0; ks < 2; ++ks) {
        float4 a = *(const float4*)(ip + ks * 32);
        float4 b = *(const float4*)(ip + ks * 32 + 4);
        bf16x8 f;
        f[0] = (__bf16)a.x; f[1] = (__bf16)a.y; f[2] = (__bf16)a.z; f[3] = (__bf16)a.w;
        f[4] = (__bf16)b.x; f[5] = (__bf16)b.y; f[6] = (__bf16)b.z; f[7] = (__bf16)b.w;
        Af[ks] = f;
    }

    f32x4 acc[4];
#pragma unroll
    for (int nt = 0; nt < 4; ++nt) { acc[nt][0] = 0.f; acc[nt][1] = 0.f; acc[nt][2] = 0.f; acc[nt][3] = 0.f; }

    if (z == 0) {
        // non-swapped: lane dim = d, reg dim = s-run of 4
#pragma unroll
        for (int nt = 0; nt < 4; ++nt) {
            acc[nt] = mfma16(Af[0], Bf[nt][0], acc[nt]);
            acc[nt] = mfma16(Af[1], Bf[nt][1], acc[nt]);
        }
#pragma unroll
        for (int nt = 0; nt < 4; ++nt) {
            int d = nt * 16 + l16;
            int scol = (wid * 16 + g * 4) ^ ((d & 7) << 3);
            bf16x4 o;
#pragma unroll
            for (int r = 0; r < 4; ++r) o[r] = (__bf16)acc[nt][r];
            *(bf16x4*)(tile + d * TP + scol) = o;   // row = d
        }
    } else {
        // swapped: lane dim = s, reg dim = e-run of 4
#pragma unroll
        for (int nt = 0; nt < 4; ++nt) {
            acc[nt] = mfma16(Bf[nt][0], Af[0], acc[nt]);
            acc[nt] = mfma16(Bf[nt][1], Af[1], acc[nt]);
        }
        const int sl = wid * 16 + l16;
        const int fk = (z == 1) ? ((sl & 7) << 3) : 0;
#pragma unroll
        for (int nt = 0; nt < 4; ++nt) {
            int e0 = (nt * 16 + g * 4) ^ fk;
            bf16x4 o;
#pragma unroll
            for (int r = 0; r < 4; ++r) o[r] = (__bf16)acc[nt][r];
            *(bf16x4*)(tile + sl * TP + e0) = o;    // row = s-local
        }
    }
    __syncthreads();

    // copy out row-linear: thread t -> row t>>2, 32B chunk (t&3)
    const int trow = threadIdx.x >> 2, tc = (threadIdx.x & 3) * 16;
    bf16x8 v0 = *(const bf16x8*)(tile + trow * TP + tc);
    bf16x8 v1 = *(const bf16x8*)(tile + trow * TP + tc + 8);
    __bf16* dst;
    if (z == 0)      dst = Vt  + ((size_t)nh * 64 + trow) * S_ + sblk + tc;
    else if (z == 1) dst = Kws + ((size_t)nh * S_ + sblk + trow) * 64 + tc;
    else             dst = Qws + ((size_t)nh * S_ + sblk + trow) * 64 + tc;
    *(bf16x8*)dst = v0;
    *(bf16x8*)(dst + 8) = v1;
}

// ----------------------------------------------------------- flash attention
// r5 structure (b128 reads, 16B swizzle, 4 waves x 32 q, grid 1024) upgraded
// to a counted-vmcnt pipeline (T4): 3 LDS buffers, 2 tiles in flight, raw
// s_barrier (no drain), inline-asm s_waitcnt vmcnt(4) so next-tile loads stay
// in flight ACROSS the barrier. Softmax = add-tree + final shfl (r5 form).
__global__ __launch_bounds__(256, 3) void k_attn(const __bf16* __restrict__ Qws,
                                                 const __bf16* __restrict__ Kws,
                                                 const __bf16* __restrict__ Vt,
                                                 const int* __restrict__ maskp,
                                                 __bf16* __restrict__ Xws) {
    __shared__ __align__(16) char lds[3][16384];  // [buf][K 8KB | V 8KB]
    const int tid = threadIdx.x, lane = tid & 63, wid = tid >> 6;
    const int l31 = lane & 31, hf = lane >> 5, h8 = hf * 8;
    // XCD swizzle: 1024 blocks = 8 xcd x (8 nh x 16 qb); XCD x -> nh [8x,8x+8)
    const int v = blockIdx.x;
    const int u = v >> 3;
    const int nh = (v & 7) * 8 + (u & 7), qb = u >> 3;
    const int n = nh >> 4, hd = nh & 15;

    int az = 0;
    for (int i = tid; i < S_; i += 256) az |= (maskp[(size_t)n * S_ + i] == 0);
    const int anyzero = __syncthreads_or(az);

    const char* Kc = (const char*)(Kws + (size_t)nh * S_ * 64);
    const char* Vc = (const char*)(Vt  + (size_t)nh * 64 * S_);
    const __bf16* Qb = Qws + (size_t)nh * S_ * 64;

    const int q0 = qb * 128 + wid * 32;
    bf16x8 Qf[4];
#pragma unroll
    for (int dt = 0; dt < 4; ++dt)
        Qf[dt] = *(const bf16x8*)(Qb + (size_t)(q0 + l31) * 64 + dt * 16 + h8);

    f32x16 acc0 = zero16(), acc1 = zero16();
    float lsum = 0.f;

    // stage one 16KB K/V tile: 4 gload_lds16 instrs per wave (vmcnt +4)
    auto stage = [&](int buf, int kb) {
        char* base = &lds[buf][0];
        const char* ks = Kc + (size_t)kb * 8192 + wid * 2048 + lane * 16;
        char* kd = base + wid * 2048;
        gload_lds16(ks, kd);
        gload_lds16(ks + 1024, kd + 1024);
        const int r0 = wid * 16 + (lane >> 3);
        const char* vs = Vc + (size_t)r0 * (S_ * 2) + (size_t)kb * 128 + (lane & 7) * 16;
        char* vd = base + 8192 + wid * 2048;
        gload_lds16(vs, vd);
        gload_lds16(vs + (size_t)8 * (S_ * 2), vd + 1024);
    };

    // fold swizzle + hf-slot into the base: every read = base ^ compile-const
    const int fold = (hf * 16) ^ ((l31 & 7) << 4);
    const int kb2 = l31 * 128 + fold;          // K row base (bits 4-6 = fold)
    const int vb2 = 8192 + l31 * 128 + fold;   // V row base

    stage(0, 0);
    stage(1, 1);
    for (int kb = 0; kb < 32; ++kb) {
        // wait for OWN tile-kb loads (oldest 4); tile kb+1's 4 stay in flight
        if (kb < 31) asm volatile("s_waitcnt vmcnt(4)" ::: "memory");
        else         asm volatile("s_waitcnt vmcnt(0)" ::: "memory");
        __builtin_amdgcn_s_barrier();          // all waves' tile-kb loads landed
        __builtin_amdgcn_sched_barrier(0);     // keep ds_reads below the barrier
        char* base = &lds[0][0] + (kb % 3) * 16384;
        const int k0 = kb * 64;
#pragma unroll
        for (int kt = 0; kt < 2; ++kt) {
            bf16x8 K0 = *(const bf16x8*)(base + ((kb2 ^  0) + kt * 4096));
            bf16x8 K1 = *(const bf16x8*)(base + ((kb2 ^ 32) + kt * 4096));
            bf16x8 K2 = *(const bf16x8*)(base + ((kb2 ^ 64) + kt * 4096));
            bf16x8 K3 = *(const bf16x8*)(base + ((kb2 ^ 96) + kt * 4096));
            __builtin_amdgcn_s_setprio(1);
            f32x16 s = zero16();
            s = mfma32(K0, Qf[0], s); s = mfma32(K1, Qf[1], s);
            s = mfma32(K2, Qf[2], s); s = mfma32(K3, Qf[3], s);
            __builtin_amdgcn_s_setprio(0);
            // issue V reads before softmax so ds latency hides under VALU
            bf16x8 V00 = *(const bf16x8*)(base + (vb2 ^ (kt * 64)));
            bf16x8 V01 = *(const bf16x8*)(base + (vb2 ^ (kt * 64 + 32)));
            bf16x8 V10 = *(const bf16x8*)(base + ((vb2 ^ (kt * 64)) + 4096));
            bf16x8 V11 = *(const bf16x8*)(base + ((vb2 ^ (kt * 64 + 32)) + 4096));
            if (anyzero) {
#pragma unroll
                for (int r = 0; r < 16; ++r) {
                    int kk = k0 + kt * 32 + (r & 3) + 8 * (r >> 2) + 4 * hf;
                    if (maskp[(size_t)n * S_ + kk] == 0) s[r] = -1e30f;
                }
            }
            float p[16];
#pragma unroll
            for (int r = 0; r < 16; ++r) p[r] = __builtin_amdgcn_exp2f(s[r]);
            lsum += ((((p[0] + p[1]) + (p[2] + p[3])) + ((p[4] + p[5]) + (p[6] + p[7])))
                  + (((p[8] + p[9]) + (p[10] + p[11])) + ((p[12] + p[13]) + (p[14] + p[15]))));
            u32 w0 = pack2(p[0],  p[1]),  w1 = pack2(p[2],  p[3]);
            u32 w2 = pack2(p[4],  p[5]),  w3 = pack2(p[6],  p[7]);
            u32 w4 = pack2(p[8],  p[9]),  w5 = pack2(p[10], p[11]);
            u32 w6 = pack2(p[12], p[13]), w7 = pack2(p[14], p[15]);
            swap32(w0, w2); swap32(w1, w3); swap32(w4, w6); swap32(w5, w7);
            u32x4 t0; t0[0] = w0; t0[1] = w1; t0[2] = w2; t0[3] = w3;
            u32x4 t1; t1[0] = w4; t1[1] = w5; t1[2] = w6; t1[3] = w7;
            bf16x8 P0 = __builtin_bit_cast(bf16x8, t0);
            bf16x8 P1 = __builtin_bit_cast(bf16x8, t1);
            __builtin_amdgcn_s_setprio(1);
            acc0 = mfma32(V00, P0, acc0); acc0 = mfma32(V01, P1, acc0);
            acc1 = mfma32(V10, P0, acc1); acc1 = mfma32(V11, P1, acc1);
            __builtin_amdgcn_s_setprio(0);
        }
        // prefetch tile kb+2 into buf (kb+2)%3 (released at the barrier above)
        if (kb < 30) stage((kb + 2) % 3, kb + 2);
    }

    lsum += __shfl_xor(lsum, 32);
    const float inv = 1.0f / lsum;
    const int qg = q0 + l31;
    __bf16* Ob = Xws + ((size_t)(n * S_ + qg)) * E_ + hd * 64;
    const int qsw = (qg & 7) << 3;

    auto store_half = [&](const f32x16& a, int dv) {
#pragma unroll
        for (int rr = 0; rr < 4; ++rr) {
            bf16x4 o;
#pragma unroll
            for (int j = 0; j < 4; ++j) o[j] = (__bf16)(a[rr * 4 + j] * inv);
            int dsw = ((dv * 32 + rr * 8) ^ qsw) + hf * 4;  // pre-swizzle for k_out
            *(bf16x4*)(Ob + dsw) = o;
        }
    };
    store_half(acc0, 0);
    store_half(acc1, 1);
}

// ------------------------------------------------------- output GEMM + bias
// 128x128 block tile, BK=64, LDS-staged (global_load_lds, double-buffered),
// swizzled ds_read_b128 (swizzle pre-applied in global X / Wob).
__global__ __launch_bounds__(256) void k_out(const __bf16* __restrict__ Xws,
                                             const __bf16* __restrict__ Wob,
                                             const float* __restrict__ bo,
                                             float* __restrict__ out) {
    __shared__ __align__(16) char Al[2][16384];
    __shared__ __align__(16) char Bl[2][16384];
    const int tid = threadIdx.x, lane = tid & 63, wid = tid >> 6;
    const int l31 = lane & 31, hf = lane >> 5;
    const int v = blockIdx.x;
    const int id2 = (v & 7) * 64 + (v >> 3);
    const int mb = id2 >> 3, ob = id2 & 7;
    const int m0 = mb * 128, o0 = ob * 128;
    const int wr = wid >> 1, wc = wid & 1;

    const char* Xb = (const char*)Xws + (size_t)m0 * 2048;
    const char* Wb = (const char*)Wob + (size_t)o0 * 2048;
    const int r = tid >> 3, cb = (tid & 7) * 16;

    auto stage = [&](int buf, int kb) {
#pragma unroll
        for (int p = 0; p < 4; ++p) {
            gload_lds16(Xb + (size_t)(p * 32 + r) * 2048 + kb * 128 + cb,
                        &Al[buf][p * 4096 + wid * 1024]);
            gload_lds16(Wb + (size_t)(p * 32 + r) * 2048 + kb * 128 + cb,
                        &Bl[buf][p * 4096 + wid * 1024]);
        }
    };

    f32x16 acc00 = zero16(), acc01 = zero16(), acc10 = zero16(), acc11 = zero16();

    const int arow0 = (wr * 64 + l31) * 128;
    const int brow0 = (wc * 64 + l31) * 128;
    const int rsw = (l31 & 7) << 4;

    stage(0, 0);
    int buf = 0;
    for (int kb = 0; kb < 16; ++kb) {
        __syncthreads();
        if (kb < 15) stage(buf ^ 1, kb + 1);
        const char* ab = &Al[buf][0];
        const char* bb = &Bl[buf][0];
#pragma unroll
        for (int ks = 0; ks < 4; ++ks) {
            const int co = (ks * 32 + hf * 16) ^ rsw;
            bf16x8 A0 = *(const bf16x8*)(ab + arow0 + co);
            bf16x8 A1 = *(const bf16x8*)(ab + arow0 + 32 * 128 + co);
            bf16x8 B0 = *(const bf16x8*)(bb + brow0 + co);
            bf16x8 B1 = *(const bf16x8*)(bb + brow0 + 32 * 128 + co);
            __builtin_amdgcn_s_setprio(1);
            acc00 = mfma32(A0, B0, acc00);
            acc01 = mfma32(A0, B1, acc01);
            acc10 = mfma32(A1, B0, acc10);
            acc11 = mfma32(A1, B1, acc11);
            __builtin_amdgcn_s_setprio(0);
        }
        buf ^= 1;
    }

    const float bias0 = bo[o0 + wc * 64 + l31];
    const float bias1 = bo[o0 + wc * 64 + 32 + l31];
#pragma unroll
    for (int sm = 0; sm < 2; ++sm) {
        const f32x16& a0 = (sm == 0) ? acc00 : acc10;
        const f32x16& a1 = (sm == 0) ? acc01 : acc11;
#pragma unroll
        for (int rr = 0; rr < 4; ++rr)
#pragma unroll
            for (int j = 0; j < 4; ++j) {
                size_t m = (size_t)m0 + wr * 64 + sm * 32 + rr * 8 + hf * 4 + j;
                out[m * E_ + o0 + wc * 64 + l31]      = a0[rr * 4 + j] + bias0;
                out[m * E_ + o0 + wc * 64 + 32 + l31] = a1[rr * 4 + j] + bias1;
            }
    }
}

extern "C" void kernel_launch(void* const* d_in, const int* in_sizes, int n_in,
                              void* d_out, int out_size, void* d_ws, size_t ws_size,
                              hipStream_t stream) {
    const float* vin  = (const float*)d_in[0];
    const float* kin  = (const float*)d_in[1];
    const float* qin  = (const float*)d_in[2];
    const int*   mask = (const int*)d_in[3];
    const float* Wv   = (const float*)d_in[4];
    const float* Wk   = (const float*)d_in[5];
    const float* Wq   = (const float*)d_in[6];
    const float* Wo   = (const float*)d_in[7];
    const float* bo   = (const float*)d_in[8];

    __bf16* Qws = (__bf16*)d_ws;                       // [64][2048][64]
    __bf16* Kws = Qws + (size_t)NH_ * S_ * 64;         // [64][2048][64] swizzled
    __bf16* Vt  = Kws + (size_t)NH_ * S_ * 64;         // [64][64][2048] swizzled
    __bf16* Xws = Vt  + (size_t)NH_ * S_ * 64;         // [4][2048][1024] swizzled
    __bf16* Wob = Xws + (size_t)4 * S_ * E_;           // [1024][1024] swizzled
    float* out = (float*)d_out;

    hipLaunchKernelGGL(k_cast_wo, dim3(512), dim3(256), 0, stream, Wo, Wob);
    hipLaunchKernelGGL(k_proj, dim3(2048, 1, 3), dim3(256), 0, stream,
                       vin, kin, qin, Wv, Wk, Wq, Qws, Kws, Vt);
    hipLaunchKernelGGL(k_attn, dim3(1024), dim3(256), 0, stream, Qws, Kws, Vt, mask, Xws);
    hipLaunchKernelGGL(k_out, dim3(512), dim3(256), 0, stream, Xws, Wob, bo, out);
}

// Round 12
// 143.626 us; speedup vs baseline: 1.2391x; 1.2076x over previous
//
#include <hip/hip_runtime.h>
#include <hip/hip_bf16.h>

typedef __bf16 bf16x8 __attribute__((ext_vector_type(8)));
typedef __bf16 bf16x4 __attribute__((ext_vector_type(4)));
typedef __bf16 bf16x2 __attribute__((ext_vector_type(2)));
typedef float  f32x4  __attribute__((ext_vector_type(4)));
typedef float  f32x16 __attribute__((ext_vector_type(16)));
typedef unsigned int u32;
typedef u32 u32x2 __attribute__((ext_vector_type(2)));
typedef u32 u32x4 __attribute__((ext_vector_type(4)));

#define S_  2048
#define E_  1024
#define NH_ 64

__device__ __forceinline__ f32x4 mfma16(bf16x8 a, bf16x8 b, f32x4 c) {
    return __builtin_amdgcn_mfma_f32_16x16x32_bf16(a, b, c, 0, 0, 0);
}
__device__ __forceinline__ f32x16 mfma32(bf16x8 a, bf16x8 b, f32x16 c) {
    return __builtin_amdgcn_mfma_f32_32x32x16_bf16(a, b, c, 0, 0, 0);
}
__device__ __forceinline__ u32 pack2(float a, float b) {
    bf16x2 t; t[0] = (__bf16)a; t[1] = (__bf16)b;
    return __builtin_bit_cast(u32, t);
}
__device__ __forceinline__ void swap32(u32& a, u32& b) {
    asm("v_permlane32_swap_b32 %0, %1" : "+v"(a), "+v"(b));
}
__device__ __forceinline__ f32x16 zero16() {
    f32x16 z;
#pragma unroll
    for (int i = 0; i < 16; ++i) z[i] = 0.f;
    return z;
}
__device__ __forceinline__ void gload_lds16(const void* g, void* l) {
    __builtin_amdgcn_global_load_lds(
        (const __attribute__((address_space(1))) unsigned int*)g,
        (__attribute__((address_space(3))) unsigned int*)l, 16, 0, 0);
}

// ------------------------------------------- Wo -> bf16 (pre-swizzled cols)
__global__ __launch_bounds__(256) void k_cast_wo(const float* __restrict__ Wo,
                                                 __bf16* __restrict__ Wob) {
    int i = (blockIdx.x * 256 + threadIdx.x) * 8;
    int o = i >> 10, e0 = i & 1023;
    float4 a = *(const float4*)(Wo + i);
    float4 b = *(const float4*)(Wo + i + 4);
    bf16x8 f;
    f[0] = (__bf16)a.x; f[1] = (__bf16)a.y; f[2] = (__bf16)a.z; f[3] = (__bf16)a.w;
    f[4] = (__bf16)b.x; f[5] = (__bf16)b.y; f[6] = (__bf16)b.z; f[7] = (__bf16)b.w;
    int e_swz = (e0 & ~63) | ((e0 & 63) ^ ((o & 7) << 3));
    *(bf16x8*)(Wob + (size_t)o * 1024 + e_swz) = f;
}

// ------------------------------------------------- QKV per-head projections
// 4x work per block: W fragments loaded ONCE, 4 x 64-row iterations through
// the LDS tile with coalesced copyout. Layouts (byte-identical to before):
// z=0 V: Vt[nh][d][s ^ ((d&7)<<3)]
// z=1 K: Kws[nh][s][e ^ ((s&7)<<3)]
// z=2 Q: Qws[nh][s][e] plain; log2(e)/32 folded into Wq.
#define TP 72   // padded LDS row stride (elems)
__global__ __launch_bounds__(256) void k_proj(const float* __restrict__ vin,
                                              const float* __restrict__ kin,
                                              const float* __restrict__ qin,
                                              const float* __restrict__ Wv,
                                              const float* __restrict__ Wk,
                                              const float* __restrict__ Wq,
                                              __bf16* __restrict__ Qws,
                                              __bf16* __restrict__ Kws,
                                              __bf16* __restrict__ Vt) {
    __shared__ __align__(16) __bf16 tile[64 * TP];   // 9 KB
    const int z = blockIdx.z;
    const float* in = (z == 0) ? vin : ((z == 1) ? kin : qin);
    const float* W  = (z == 0) ? Wv  : ((z == 1) ? Wk  : Wq);
    const float scale = (z == 2) ? 0.04508422f : 1.0f;  // log2(e)/32
    const int bid  = blockIdx.x;                 // 512 blocks: 64 nh x 8 groups
    const int nh   = bid >> 3;
    const int sbase = (bid & 7) << 8;            // 256 rows per block
    const int n = nh >> 4, h = nh & 15;
    const int lane = threadIdx.x & 63, wid = threadIdx.x >> 6;
    const int l16 = lane & 15, g = lane >> 4;

    // W fragments: loop-invariant, loaded once per block
    bf16x8 Bf[4][2];
#pragma unroll
    for (int nt = 0; nt < 4; ++nt)
#pragma unroll
        for (int ks = 0; ks < 2; ++ks) {
            const float* wp = W + (nt * 16 + l16) * 64 + ks * 32 + g * 8;
            float4 a = *(const float4*)wp;
            float4 b = *(const float4*)(wp + 4);
            bf16x8 f;
            f[0] = (__bf16)(a.x * scale); f[1] = (__bf16)(a.y * scale);
            f[2] = (__bf16)(a.z * scale); f[3] = (__bf16)(a.w * scale);
            f[4] = (__bf16)(b.x * scale); f[5] = (__bf16)(b.y * scale);
            f[6] = (__bf16)(b.z * scale); f[7] = (__bf16)(b.w * scale);
            Bf[nt][ks] = f;
        }

    for (int it = 0; it < 4; ++it) {
        const int sblk = sbase + it * 64;
        const int s = sblk + wid * 16 + l16;
        const float* ip = in + ((size_t)n * S_ + s) * E_ + h * 64 + g * 8;
        bf16x8 Af[2];
#pragma unroll
        for (int ks = 0; ks < 2; ++ks) {
            float4 a = *(const float4*)(ip + ks * 32);
            float4 b = *(const float4*)(ip + ks * 32 + 4);
            bf16x8 f;
            f[0] = (__bf16)a.x; f[1] = (__bf16)a.y; f[2] = (__bf16)a.z; f[3] = (__bf16)a.w;
            f[4] = (__bf16)b.x; f[5] = (__bf16)b.y; f[6] = (__bf16)b.z; f[7] = (__bf16)b.w;
            Af[ks] = f;
        }

        f32x4 acc[4];
#pragma unroll
        for (int nt = 0; nt < 4; ++nt) { acc[nt][0] = 0.f; acc[nt][1] = 0.f; acc[nt][2] = 0.f; acc[nt][3] = 0.f; }

        if (it > 0) __syncthreads();   // tile free from previous copyout
        if (z == 0) {
            // non-swapped: lane dim = d, reg dim = s-run of 4
#pragma unroll
            for (int nt = 0; nt < 4; ++nt) {
                acc[nt] = mfma16(Af[0], Bf[nt][0], acc[nt]);
                acc[nt] = mfma16(Af[1], Bf[nt][1], acc[nt]);
            }
#pragma unroll
            for (int nt = 0; nt < 4; ++nt) {
                int d = nt * 16 + l16;
                int scol = (wid * 16 + g * 4) ^ ((d & 7) << 3);
                bf16x4 o;
#pragma unroll
                for (int r = 0; r < 4; ++r) o[r] = (__bf16)acc[nt][r];
                *(bf16x4*)(tile + d * TP + scol) = o;   // row = d
            }
        } else {
            // swapped: lane dim = s, reg dim = e-run of 4
#pragma unroll
            for (int nt = 0; nt < 4; ++nt) {
                acc[nt] = mfma16(Bf[nt][0], Af[0], acc[nt]);
                acc[nt] = mfma16(Bf[nt][1], Af[1], acc[nt]);
            }
            const int sl = wid * 16 + l16;
            const int fk = (z == 1) ? ((sl & 7) << 3) : 0;
#pragma unroll
            for (int nt = 0; nt < 4; ++nt) {
                int e0 = (nt * 16 + g * 4) ^ fk;
                bf16x4 o;
#pragma unroll
                for (int r = 0; r < 4; ++r) o[r] = (__bf16)acc[nt][r];
                *(bf16x4*)(tile + sl * TP + e0) = o;    // row = s-local
            }
        }
        __syncthreads();

        // copy out row-linear: thread t -> row t>>2, 32B chunk (t&3)
        const int trow = threadIdx.x >> 2, tc = (threadIdx.x & 3) * 16;
        bf16x8 v0 = *(const bf16x8*)(tile + trow * TP + tc);
        bf16x8 v1 = *(const bf16x8*)(tile + trow * TP + tc + 8);
        __bf16* dst;
        if (z == 0)      dst = Vt  + ((size_t)nh * 64 + trow) * S_ + sblk + tc;
        else if (z == 1) dst = Kws + ((size_t)nh * S_ + sblk + trow) * 64 + tc;
        else             dst = Qws + ((size_t)nh * S_ + sblk + trow) * 64 + tc;
        *(bf16x8*)dst = v0;
        *(bf16x8*)(dst + 8) = v1;
    }
}

// ----------------------------------------------------------- flash attention
// r5-verbatim (proven 87us): 4 waves x 32 q, grid 1024, lb(256,4), b128 reads
// with 16B-granularity XOR swizzle (pre-applied in global), double-buffered
// global_load_lds staging, in-register softmax (exp2 -> cvt_pk -> permlane).
__global__ __launch_bounds__(256, 4) void k_attn(const __bf16* __restrict__ Qws,
                                                 const __bf16* __restrict__ Kws,
                                                 const __bf16* __restrict__ Vt,
                                                 const int* __restrict__ maskp,
                                                 __bf16* __restrict__ Xws) {
    __shared__ __align__(16) char lds[2][16384];  // [buf][K 8KB | V 8KB]
    const int tid = threadIdx.x, lane = tid & 63, wid = tid >> 6;
    const int l31 = lane & 31, hf = lane >> 5, h8 = hf * 8;
    // XCD swizzle: 1024 blocks = 8 xcd x (8 nh x 16 qb); XCD x -> nh [8x,8x+8)
    const int v = blockIdx.x;
    const int u = v >> 3;
    const int nh = (v & 7) * 8 + (u & 7), qb = u >> 3;
    const int n = nh >> 4, hd = nh & 15;

    int az = 0;
    for (int i = tid; i < S_; i += 256) az |= (maskp[(size_t)n * S_ + i] == 0);
    const int anyzero = __syncthreads_or(az);

    const char* Kc = (const char*)(Kws + (size_t)nh * S_ * 64);
    const char* Vc = (const char*)(Vt  + (size_t)nh * 64 * S_);
    const __bf16* Qb = Qws + (size_t)nh * S_ * 64;

    const int q0 = qb * 128 + wid * 32;
    bf16x8 Qf[4];
#pragma unroll
    for (int dt = 0; dt < 4; ++dt)
        Qf[dt] = *(const bf16x8*)(Qb + (size_t)(q0 + l31) * 64 + dt * 16 + h8);

    f32x16 acc0 = zero16(), acc1 = zero16();
    float lsum = 0.f;

    // stage 16KB with 256 threads: 4 x gload_lds16 per thread
    auto stage = [&](int buf, int kb) {
        char* base = &lds[buf][0];
        const char* ks = Kc + (size_t)kb * 8192 + wid * 2048 + lane * 16;
        char* kd = base + wid * 2048;
        gload_lds16(ks, kd);
        gload_lds16(ks + 1024, kd + 1024);
        const int r0 = wid * 16 + (lane >> 3);
        const char* vs = Vc + (size_t)r0 * (S_ * 2) + (size_t)kb * 128 + (lane & 7) * 16;
        char* vd = base + 8192 + wid * 2048;
        gload_lds16(vs, vd);
        gload_lds16(vs + (size_t)8 * (S_ * 2), vd + 1024);
    };

    const int swz = (l31 & 7) << 4;

    stage(0, 0);
    int buf = 0;
    for (int kb = 0; kb < 32; ++kb) {
        __syncthreads();
        if (kb < 31) stage(buf ^ 1, kb + 1);
        char* base = &lds[buf][0];
        char* vbase = base + 8192;
        const int k0 = kb * 64;
#pragma unroll
        for (int kt = 0; kt < 2; ++kt) {
            bf16x8 K0 = *(const bf16x8*)(base + (kt * 32 + l31) * 128 + (((0 * 2 + hf) * 16) ^ swz));
            bf16x8 K1 = *(const bf16x8*)(base + (kt * 32 + l31) * 128 + (((1 * 2 + hf) * 16) ^ swz));
            bf16x8 K2 = *(const bf16x8*)(base + (kt * 32 + l31) * 128 + (((2 * 2 + hf) * 16) ^ swz));
            bf16x8 K3 = *(const bf16x8*)(base + (kt * 32 + l31) * 128 + (((3 * 2 + hf) * 16) ^ swz));
            __builtin_amdgcn_s_setprio(1);
            f32x16 sA = zero16();
            sA = mfma32(K0, Qf[0], sA); sA = mfma32(K1, Qf[1], sA);
            sA = mfma32(K2, Qf[2], sA); sA = mfma32(K3, Qf[3], sA);
            __builtin_amdgcn_s_setprio(0);
            if (anyzero) {
#pragma unroll
                for (int r = 0; r < 16; ++r) {
                    int kk = k0 + kt * 32 + (r & 3) + 8 * (r >> 2) + 4 * hf;
                    if (maskp[(size_t)n * S_ + kk] == 0) sA[r] = -1e30f;
                }
            }
            float p[16];
#pragma unroll
            for (int r = 0; r < 16; ++r) p[r] = __builtin_amdgcn_exp2f(sA[r]);
            lsum += ((((p[0] + p[1]) + (p[2] + p[3])) + ((p[4] + p[5]) + (p[6] + p[7])))
                  + (((p[8] + p[9]) + (p[10] + p[11])) + ((p[12] + p[13]) + (p[14] + p[15]))));
            u32 w0 = pack2(p[0],  p[1]),  w1 = pack2(p[2],  p[3]);
            u32 w2 = pack2(p[4],  p[5]),  w3 = pack2(p[6],  p[7]);
            u32 w4 = pack2(p[8],  p[9]),  w5 = pack2(p[10], p[11]);
            u32 w6 = pack2(p[12], p[13]), w7 = pack2(p[14], p[15]);
            swap32(w0, w2); swap32(w1, w3); swap32(w4, w6); swap32(w5, w7);
            u32x4 t0; t0[0] = w0; t0[1] = w1; t0[2] = w2; t0[3] = w3;
            u32x4 t1; t1[0] = w4; t1[1] = w5; t1[2] = w6; t1[3] = w7;
            bf16x8 P0 = __builtin_bit_cast(bf16x8, t0);
            bf16x8 P1 = __builtin_bit_cast(bf16x8, t1);
            bf16x8 V00 = *(const bf16x8*)(vbase + (0 * 32 + l31) * 128 + ((((kt * 2 + 0) * 2 + hf) * 16) ^ swz));
            bf16x8 V01 = *(const bf16x8*)(vbase + (0 * 32 + l31) * 128 + ((((kt * 2 + 1) * 2 + hf) * 16) ^ swz));
            bf16x8 V10 = *(const bf16x8*)(vbase + (1 * 32 + l31) * 128 + ((((kt * 2 + 0) * 2 + hf) * 16) ^ swz));
            bf16x8 V11 = *(const bf16x8*)(vbase + (1 * 32 + l31) * 128 + ((((kt * 2 + 1) * 2 + hf) * 16) ^ swz));
            __builtin_amdgcn_s_setprio(1);
            acc0 = mfma32(V00, P0, acc0); acc0 = mfma32(V01, P1, acc0);
            acc1 = mfma32(V10, P0, acc1); acc1 = mfma32(V11, P1, acc1);
            __builtin_amdgcn_s_setprio(0);
        }
        buf ^= 1;
    }

    lsum += __shfl_xor(lsum, 32);
    const float inv = 1.0f / lsum;
    const int qg = q0 + l31;
    __bf16* Ob = Xws + ((size_t)(n * S_ + qg)) * E_ + hd * 64;
    const int qsw = (qg & 7) << 3;

    auto store_half = [&](const f32x16& a, int dv) {
#pragma unroll
        for (int rr = 0; rr < 4; ++rr) {
            bf16x4 o;
#pragma unroll
            for (int j = 0; j < 4; ++j) o[j] = (__bf16)(a[rr * 4 + j] * inv);
            int dsw = ((dv * 32 + rr * 8) ^ qsw) + hf * 4;  // pre-swizzle for k_out
            *(bf16x4*)(Ob + dsw) = o;
        }
    };
    store_half(acc0, 0);
    store_half(acc1, 1);
}

// ------------------------------------------------------- output GEMM + bias
// 128x128 block tile, BK=64, LDS-staged (global_load_lds, double-buffered),
// swizzled ds_read_b128 (swizzle pre-applied in global X / Wob).
__global__ __launch_bounds__(256) void k_out(const __bf16* __restrict__ Xws,
                                             const __bf16* __restrict__ Wob,
                                             const float* __restrict__ bo,
                                             float* __restrict__ out) {
    __shared__ __align__(16) char Al[2][16384];
    __shared__ __align__(16) char Bl[2][16384];
    const int tid = threadIdx.x, lane = tid & 63, wid = tid >> 6;
    const int l31 = lane & 31, hf = lane >> 5;
    const int v = blockIdx.x;
    const int id2 = (v & 7) * 64 + (v >> 3);
    const int mb = id2 >> 3, ob = id2 & 7;
    const int m0 = mb * 128, o0 = ob * 128;
    const int wr = wid >> 1, wc = wid & 1;

    const char* Xb = (const char*)Xws + (size_t)m0 * 2048;
    const char* Wb = (const char*)Wob + (size_t)o0 * 2048;
    const int r = tid >> 3, cb = (tid & 7) * 16;

    auto stage = [&](int buf, int kb) {
#pragma unroll
        for (int p = 0; p < 4; ++p) {
            gload_lds16(Xb + (size_t)(p * 32 + r) * 2048 + kb * 128 + cb,
                        &Al[buf][p * 4096 + wid * 1024]);
            gload_lds16(Wb + (size_t)(p * 32 + r) * 2048 + kb * 128 + cb,
                        &Bl[buf][p * 4096 + wid * 1024]);
        }
    };

    f32x16 acc00 = zero16(), acc01 = zero16(), acc10 = zero16(), acc11 = zero16();

    const int arow0 = (wr * 64 + l31) * 128;
    const int brow0 = (wc * 64 + l31) * 128;
    const int rsw = (l31 & 7) << 4;

    stage(0, 0);
    int buf = 0;
    for (int kb = 0; kb < 16; ++kb) {
        __syncthreads();
        if (kb < 15) stage(buf ^ 1, kb + 1);
        const char* ab = &Al[buf][0];
        const char* bb = &Bl[buf][0];
#pragma unroll
        for (int ks = 0; ks < 4; ++ks) {
            const int co = (ks * 32 + hf * 16) ^ rsw;
            bf16x8 A0 = *(const bf16x8*)(ab + arow0 + co);
            bf16x8 A1 = *(const bf16x8*)(ab + arow0 + 32 * 128 + co);
            bf16x8 B0 = *(const bf16x8*)(bb + brow0 + co);
            bf16x8 B1 = *(const bf16x8*)(bb + brow0 + 32 * 128 + co);
            __builtin_amdgcn_s_setprio(1);
            acc00 = mfma32(A0, B0, acc00);
            acc01 = mfma32(A0, B1, acc01);
            acc10 = mfma32(A1, B0, acc10);
            acc11 = mfma32(A1, B1, acc11);
            __builtin_amdgcn_s_setprio(0);
        }
        buf ^= 1;
    }

    const float bias0 = bo[o0 + wc * 64 + l31];
    const float bias1 = bo[o0 + wc * 64 + 32 + l31];
#pragma unroll
    for (int sm = 0; sm < 2; ++sm) {
        const f32x16& a0 = (sm == 0) ? acc00 : acc10;
        const f32x16& a1 = (sm == 0) ? acc01 : acc11;
#pragma unroll
        for (int rr = 0; rr < 4; ++rr)
#pragma unroll
            for (int j = 0; j < 4; ++j) {
                size_t m = (size_t)m0 + wr * 64 + sm * 32 + rr * 8 + hf * 4 + j;
                out[m * E_ + o0 + wc * 64 + l31]      = a0[rr * 4 + j] + bias0;
                out[m * E_ + o0 + wc * 64 + 32 + l31] = a1[rr * 4 + j] + bias1;
            }
    }
}

extern "C" void kernel_launch(void* const* d_in, const int* in_sizes, int n_in,
                              void* d_out, int out_size, void* d_ws, size_t ws_size,
                              hipStream_t stream) {
    const float* vin  = (const float*)d_in[0];
    const float* kin  = (const float*)d_in[1];
    const float* qin  = (const float*)d_in[2];
    const int*   mask = (const int*)d_in[3];
    const float* Wv   = (const float*)d_in[4];
    const float* Wk   = (const float*)d_in[5];
    const float* Wq   = (const float*)d_in[6];
    const float* Wo   = (const float*)d_in[7];
    const float* bo   = (const float*)d_in[8];

    __bf16* Qws = (__bf16*)d_ws;                       // [64][2048][64]
    __bf16* Kws = Qws + (size_t)NH_ * S_ * 64;         // [64][2048][64] swizzled
    __bf16* Vt  = Kws + (size_t)NH_ * S_ * 64;         // [64][64][2048] swizzled
    __bf16* Xws = Vt  + (size_t)NH_ * S_ * 64;         // [4][2048][1024] swizzled
    __bf16* Wob = Xws + (size_t)4 * S_ * E_;           // [1024][1024] swizzled
    float* out = (float*)d_out;

    hipLaunchKernelGGL(k_cast_wo, dim3(512), dim3(256), 0, stream, Wo, Wob);
    hipLaunchKernelGGL(k_proj, dim3(512, 1, 3), dim3(256), 0, stream,
                       vin, kin, qin, Wv, Wk, Wq, Qws, Kws, Vt);
    hipLaunchKernelGGL(k_attn, dim3(1024), dim3(256), 0, stream, Qws, Kws, Vt, mask, Xws);
    hipLaunchKernelGGL(k_out, dim3(512), dim3(256), 0, stream, Xws, Wob, bo, out);
}